// Round 2
// baseline (890.425 us; speedup 1.0000x reference)
//
#include <hip/hip_runtime.h>

#define NNODES 20000
#define FIN 64
#define HDIM 512
#define NEDGE 160000

typedef _Float16 f16;
typedef _Float16 f16x8 __attribute__((ext_vector_type(8)));
typedef float f32x4 __attribute__((ext_vector_type(4)));

#define SLICE ((size_t)NNODES * HDIM)      // elements per [20000,512] slice
#define HH ((size_t)HDIM * HDIM)           // 262144

// ---------------------------------------------------------------- helpers
__device__ __forceinline__ void async_lds16(const void* g, void* lds_base) {
  __builtin_amdgcn_global_load_lds(
      (const __attribute__((address_space(1))) void*)g,
      (__attribute__((address_space(3))) void*)lds_base, 16, 0, 0);
}

// ---------------------------------------------------------------- trivial kernels
__global__ void k_zero(int* p, int n) {
  int i = blockIdx.x * 256 + threadIdx.x;
  if (i < n) p[i] = 0;
}

__global__ void k_cvt_x(const float* __restrict__ x, f16* __restrict__ xb, int n) {
  int i = blockIdx.x * 256 + threadIdx.x;
  if (i < n) xb[i] = (f16)x[i];
}

// W_in [5][64][512] -> Wint [5][512][64] (transposed per type)
__global__ void k_cvt_win(const float* __restrict__ W, f16* __restrict__ Wt) {
  int i = blockIdx.x * 256 + threadIdx.x;
  if (i >= 5 * 512 * 64) return;
  int t = i >> 15;
  int rem = i & 32767;
  int nn = rem >> 6;
  int kk = rem & 63;
  Wt[i] = (f16)W[(size_t)t * 32768 + (size_t)kk * 512 + nn];
}

// W1/W2 [2][6][512][512] -> transposed f16, compacted to 6 used (l,t) slots
// slot p -> (l*6+t): 0->(0,0) 1->(0,1) 2->(0,3) 3->(0,4) 4->(1,1) 5->(1,4)
__global__ void k_cvt_w12(const float* __restrict__ W1, const float* __restrict__ W2,
                          f16* __restrict__ W1t, f16* __restrict__ W2t) {
  const int LT[6] = {0, 1, 3, 4, 7, 10};
  int i = blockIdx.x * 256 + threadIdx.x;
  if (i >= 6 * 262144) return;
  int p = i >> 18;
  int rem = i & 262143;
  int nn = rem >> 9;
  int kk = rem & 511;
  size_t src = (size_t)LT[p] * 262144 + (size_t)kk * 512 + nn;
  size_t dst = (size_t)p * 262144 + (size_t)nn * 512 + kk;
  W1t[dst] = (f16)W1[src];
  W2t[dst] = (f16)W2[src];
}

// ---------------------------------------------------------------- CSR build
// csr slots c: 0->edge type0, 1->t1, 2->t3, 3->t4
__global__ void k_hist(const int* __restrict__ edges, int* __restrict__ deg) {
  const int TMAP[4] = {0, 1, 3, 4};
  int c = blockIdx.y;
  int t = TMAP[c];
  int e = blockIdx.x * 256 + threadIdx.x;
  if (e < NEDGE) {
    int dst = edges[(size_t)t * 2 * NEDGE + NEDGE + e];
    atomicAdd(&deg[c * NNODES + dst], 1);
  }
}

__global__ void k_scan(const int* __restrict__ deg, int* __restrict__ offs,
                       int* __restrict__ cursor) {
  int c = blockIdx.x;
  const int* d = deg + (size_t)c * NNODES;
  int* o = offs + (size_t)c * NNODES;
  int* cu = cursor + (size_t)c * NNODES;
  __shared__ int sums[256];
  int tid = threadIdx.x;
  const int CH = 79;  // 256*79 >= 20000
  int start = tid * CH;
  int end = min(start + CH, NNODES);
  int s = 0;
  for (int i = start; i < end; ++i) s += d[i];
  sums[tid] = s;
  __syncthreads();
  for (int off = 1; off < 256; off <<= 1) {
    int v = (tid >= off) ? sums[tid - off] : 0;
    __syncthreads();
    sums[tid] += v;
    __syncthreads();
  }
  int run = sums[tid] - s;  // exclusive prefix
  for (int i = start; i < end; ++i) {
    o[i] = run;
    cu[i] = run;
    run += d[i];
  }
}

__global__ void k_scatter(const int* __restrict__ edges, int* __restrict__ cursor,
                          int* __restrict__ csr) {
  const int TMAP[4] = {0, 1, 3, 4};
  int c = blockIdx.y;
  int t = TMAP[c];
  int e = blockIdx.x * 256 + threadIdx.x;
  if (e < NEDGE) {
    int src = edges[(size_t)t * 2 * NEDGE + e];
    int dst = edges[(size_t)t * 2 * NEDGE + NEDGE + e];
    int slot = atomicAdd(&cursor[c * NNODES + dst], 1);
    csr[(size_t)c * NEDGE + slot] = src;
  }
}

// ---------------------------------------------------------------- aggregation
struct AggBatch {
  const f16* src[4];
  const f16* dst[4];
  const int* offs[4];
  const int* rend[4];  // cursor after scatter == row end
  const int* csr[4];
  f16* out[4];
};

__global__ __launch_bounds__(256) void k_agg(AggBatch ab) {
  int j = blockIdx.y;
  int i = blockIdx.x * 4 + (threadIdx.x >> 6);
  int lane = threadIdx.x & 63;
  const f16* hd = ab.dst[j] + (size_t)i * HDIM + lane * 8;
  float acc[8];
  f16x8 v = *(const f16x8*)hd;
#pragma unroll
  for (int q = 0; q < 8; ++q) acc[q] = (float)v[q];
  int e = ab.offs[j][i];
  int e1 = ab.rend[j][i];
  const int* cs = ab.csr[j];
  const f16* hs = ab.src[j];
  for (; e + 1 < e1; e += 2) {
    int s0 = cs[e], s1 = cs[e + 1];
    f16x8 u0 = *(const f16x8*)(hs + (size_t)s0 * HDIM + lane * 8);
    f16x8 u1 = *(const f16x8*)(hs + (size_t)s1 * HDIM + lane * 8);
#pragma unroll
    for (int q = 0; q < 8; ++q) acc[q] += (float)u0[q] + (float)u1[q];
  }
  if (e < e1) {
    int s0 = cs[e];
    f16x8 u0 = *(const f16x8*)(hs + (size_t)s0 * HDIM + lane * 8);
#pragma unroll
    for (int q = 0; q < 8; ++q) acc[q] += (float)u0[q];
  }
  f16x8 o;
#pragma unroll
  for (int q = 0; q < 8; ++q) o[q] = (f16)acc[q];
  *(f16x8*)(ab.out[j] + (size_t)i * HDIM + lane * 8) = o;
}

// ---------------------------------------------------------------- GEMM (C = A @ Bt^T)
// A [M,K] f16 row-major (ldA), Bt [512,K] f16 row-major (W pre-transposed).
// flags: 1=relu, 2=add prev (f32), 4=store f16 (else f32). N fixed = 512.
struct GemmBatch {
  const f16* A[6];
  const f16* B[6];
  const float* bias[6];
  const float* prev[6];
  void* D[6];
  int flags[6];
};

__global__ __launch_bounds__(256) void k_gemm(GemmBatch gb, int M, int K, int ldA) {
  __shared__ f16 lA[128 * 32];
  __shared__ f16 lB[128 * 32];
  const int z = blockIdx.z;
  const f16* __restrict__ A = gb.A[z];
  const f16* __restrict__ Bt = gb.B[z];
  const int flags = gb.flags[z];
  const int tid = threadIdx.x;
  const int lane = tid & 63;
  const int wave = tid >> 6;
  const int m0 = blockIdx.x * 128;
  const int n0 = blockIdx.y * 128;
  const int wm = wave & 1, wn = wave >> 1;
  const int fr = lane & 15, fq = lane >> 4;
  const int r0 = tid >> 2;         // staging row within 64-row half
  const int co = (tid & 3) * 8;    // staging col offset in elements

  f32x4 acc[4][4];
#pragma unroll
  for (int a = 0; a < 4; ++a)
#pragma unroll
    for (int b = 0; b < 4; ++b) acc[a][b] = (f32x4){0.f, 0.f, 0.f, 0.f};

  for (int kk = 0; kk < K; kk += 32) {
    int ra0 = min(m0 + r0, M - 1);
    int ra1 = min(m0 + 64 + r0, M - 1);
    async_lds16(A + (size_t)ra0 * ldA + kk + co, (char*)lA + wave * 1024);
    async_lds16(A + (size_t)ra1 * ldA + kk + co, (char*)lA + 4096 + wave * 1024);
    async_lds16(Bt + (size_t)(n0 + r0) * K + kk + co, (char*)lB + wave * 1024);
    async_lds16(Bt + (size_t)(n0 + 64 + r0) * K + kk + co, (char*)lB + 4096 + wave * 1024);
    __syncthreads();
    f16x8 af[4], bf[4];
#pragma unroll
    for (int t = 0; t < 4; ++t)
      af[t] = *(const f16x8*)&lA[(wm * 64 + t * 16 + fr) * 32 + fq * 8];
#pragma unroll
    for (int t = 0; t < 4; ++t)
      bf[t] = *(const f16x8*)&lB[(wn * 64 + t * 16 + fr) * 32 + fq * 8];
#pragma unroll
    for (int mt = 0; mt < 4; ++mt)
#pragma unroll
      for (int nt = 0; nt < 4; ++nt)
        acc[mt][nt] = __builtin_amdgcn_mfma_f32_16x16x32_f16(af[mt], bf[nt], acc[mt][nt], 0, 0, 0);
    __syncthreads();
  }

  const float* __restrict__ bias = gb.bias[z];
  const float* __restrict__ prev = gb.prev[z];
#pragma unroll
  for (int nt = 0; nt < 4; ++nt) {
    const int col = n0 + wn * 64 + nt * 16 + fr;
    const float bv = bias[col];
#pragma unroll
    for (int mt = 0; mt < 4; ++mt) {
      const int rowb = m0 + wm * 64 + mt * 16 + fq * 4;
#pragma unroll
      for (int r = 0; r < 4; ++r) {
        int row = rowb + r;
        if (row < M) {
          float v = acc[mt][nt][r] + bv;
          if (flags & 2) v += prev[(size_t)row * HDIM + col];
          if (flags & 1) v = fmaxf(v, 0.f);
          if (flags & 4)
            ((f16*)gb.D[z])[(size_t)row * HDIM + col] = (f16)v;
          else
            ((float*)gb.D[z])[(size_t)row * HDIM + col] = v;
        }
      }
    }
  }
}

// ---------------------------------------------------------------- head
__global__ __launch_bounds__(256) void k_head(const float* __restrict__ out0,
                                              const float* __restrict__ Wout,
                                              const float* __restrict__ bout,
                                              float* __restrict__ y) {
  int i = blockIdx.x * 4 + (threadIdx.x >> 6);
  int lane = threadIdx.x & 63;
  const float4* row = (const float4*)(out0 + (size_t)i * HDIM);
  const float4* w = (const float4*)Wout;
  float4 a = row[lane], b = row[64 + lane];
  float4 wa = w[lane], wb = w[64 + lane];
  float s = fmaxf(a.x, 0.f) * wa.x + fmaxf(a.y, 0.f) * wa.y +
            fmaxf(a.z, 0.f) * wa.z + fmaxf(a.w, 0.f) * wa.w +
            fmaxf(b.x, 0.f) * wb.x + fmaxf(b.y, 0.f) * wb.y +
            fmaxf(b.z, 0.f) * wb.z + fmaxf(b.w, 0.f) * wb.w;
#pragma unroll
  for (int m = 32; m; m >>= 1) s += __shfl_xor(s, m, 64);
  if (lane == 0) y[i] = s + bout[0];
}

// ---------------------------------------------------------------- launch
extern "C" void kernel_launch(void* const* d_in, const int* in_sizes, int n_in,
                              void* d_out, int out_size, void* d_ws, size_t ws_size,
                              hipStream_t stream) {
  const float* x_all = (const float*)d_in[0];
  const float* W_in = (const float*)d_in[1];
  const float* b_in = (const float*)d_in[2];
  const float* W1 = (const float*)d_in[3];
  const float* b1 = (const float*)d_in[4];
  const float* W2 = (const float*)d_in[5];
  const float* b2 = (const float*)d_in[6];
  const float* W_out = (const float*)d_in[7];
  const float* b_out = (const float*)d_in[8];
  const int* edges = (const int*)d_in[9];

  // ---- workspace carve (~207 MB; pool of 9 f16 slices with liveness aliasing)
  char* p = (char*)d_ws;
  auto take = [&](size_t bytes) {
    char* r = p;
    p += (bytes + 255) & ~(size_t)255;
    return r;
  };
  f16* xb = (f16*)take((size_t)5 * NNODES * FIN * 2);       // 12.8 MB
  f16* Wint = (f16*)take((size_t)5 * HDIM * FIN * 2);       // 0.33 MB
  f16* W1t = (f16*)take((size_t)6 * HH * 2);                // 3.15 MB
  f16* W2t = (f16*)take((size_t)6 * HH * 2);                // 3.15 MB
  int* deg = (int*)take((size_t)4 * NNODES * 4);
  int* offs = (int*)take((size_t)4 * NNODES * 4);
  int* cursor = (int*)take((size_t)4 * NNODES * 4);
  int* csr = (int*)take((size_t)4 * NEDGE * 4);             // 2.56 MB
  f16* pool = (f16*)take((size_t)9 * SLICE * 2);            // 184.3 MB
  auto P = [&](int s) { return pool + (size_t)s * SLICE; };
  float* out0 = (float*)P(7);  // f32, spans slices P7+P8

  // ---- prep: conversions + CSR build
  k_zero<<<(4 * NNODES + 255) / 256, 256, 0, stream>>>(deg, 4 * NNODES);
  k_cvt_x<<<(5 * NNODES * FIN) / 256, 256, 0, stream>>>(x_all, xb, 5 * NNODES * FIN);
  k_cvt_win<<<640, 256, 0, stream>>>(W_in, Wint);
  k_cvt_w12<<<6144, 256, 0, stream>>>(W1, W2, W1t, W2t);
  k_hist<<<dim3(625, 4), 256, 0, stream>>>(edges, deg);
  k_scan<<<4, 256, 0, stream>>>(deg, offs, cursor);
  k_scatter<<<dim3(625, 4), 256, 0, stream>>>(edges, cursor, csr);

  const dim3 gemm_grid(157, 4, 1);

  // ---- input projection: h0[t] = relu(x[t] @ W_in[t] + b_in[t])
  // h0 slices by type: 0->P0, 1->P1, 2->P2, 3->P3, 4->P7
  {
    const int hs[5] = {0, 1, 2, 3, 7};
    GemmBatch g{};
    for (int t = 0; t < 5; ++t) {
      g.A[t] = xb + (size_t)t * NNODES * FIN;
      g.B[t] = Wint + (size_t)t * HDIM * FIN;
      g.bias[t] = b_in + (size_t)t * HDIM;
      g.prev[t] = nullptr;
      g.D[t] = P(hs[t]);
      g.flags[t] = 1 | 4;
    }
    k_gemm<<<dim3(157, 4, 5), 256, 0, stream>>>(g, NNODES, FIN, FIN);
  }

  // ---- layer 0 aggregations (j: 0=t1, 1=t4, 2=t0, 3=t3)
  // agg outputs: t1->P4, t4->P5, t0->P6, t3->P8
  {
    AggBatch a{};
    // t1: (s=1,d=0), csr slot 1
    a.src[0] = P(1); a.dst[0] = P(0);
    a.offs[0] = offs + 1 * NNODES; a.rend[0] = cursor + 1 * NNODES;
    a.csr[0] = csr + (size_t)1 * NEDGE; a.out[0] = P(4);
    // t4: (s=3,d=0), csr slot 3
    a.src[1] = P(3); a.dst[1] = P(0);
    a.offs[1] = offs + 3 * NNODES; a.rend[1] = cursor + 3 * NNODES;
    a.csr[1] = csr + (size_t)3 * NEDGE; a.out[1] = P(5);
    // t0: (s=4,d=1), csr slot 0
    a.src[2] = P(7); a.dst[2] = P(1);
    a.offs[2] = offs + 0 * NNODES; a.rend[2] = cursor + 0 * NNODES;
    a.csr[2] = csr + (size_t)0 * NEDGE; a.out[2] = P(6);
    // t3: (s=2,d=3), csr slot 2
    a.src[3] = P(2); a.dst[3] = P(3);
    a.offs[3] = offs + 2 * NNODES; a.rend[3] = cursor + 2 * NNODES;
    a.csr[3] = csr + (size_t)2 * NEDGE; a.out[3] = P(8);
    k_agg<<<dim3(5000, 4), 256, 0, stream>>>(a);
  }

  // ---- layer 0 MLP first GEMMs (h0 dead -> zb reuses P0..P3)
  // z_t1->P0, z_t4->P1, z_t0->P2, z_t3->P3; W1t compact slots: t1->1, t4->3, t0->0, t3->2
  {
    const int aj[4] = {4, 5, 6, 8};    // agg inputs
    const int wj[4] = {1, 3, 0, 2};    // compact W slot
    const int bj[4] = {1, 4, 0, 3};    // b1 index (l=0)
    GemmBatch g{};
    for (int j = 0; j < 4; ++j) {
      g.A[j] = P(aj[j]);
      g.B[j] = W1t + (size_t)wj[j] * HH;
      g.bias[j] = b1 + (size_t)bj[j] * HDIM;
      g.prev[j] = nullptr;
      g.D[j] = P(j);
      g.flags[j] = 1 | 4;
    }
    k_gemm<<<dim3(157, 4, 4), 256, 0, stream>>>(g, NNODES, HDIM, HDIM);
  }

  // ---- layer 0 second GEMMs
  {  // t1 -> out0 (f32, no relu, beta=0); out0 = [P7,P8] (both dead)
    GemmBatch g{};
    g.A[0] = P(0); g.B[0] = W2t + 1 * HH; g.bias[0] = b2 + 1 * HDIM;
    g.prev[0] = nullptr; g.D[0] = out0; g.flags[0] = 0;
    k_gemm<<<gemm_grid, 256, 0, stream>>>(g, NNODES, HDIM, HDIM);
  }
  {  // t4 -> h1_type0 = relu(out0 + y) (f16) -> P4
    GemmBatch g{};
    g.A[0] = P(1); g.B[0] = W2t + 3 * HH; g.bias[0] = b2 + 4 * HDIM;
    g.prev[0] = out0; g.D[0] = P(4); g.flags[0] = 1 | 2 | 4;
    k_gemm<<<gemm_grid, 256, 0, stream>>>(g, NNODES, HDIM, HDIM);
  }
  {  // t0 -> h1_type1 -> P5 ; t3 -> h1_type3 -> P6 (batched)
    GemmBatch g{};
    g.A[0] = P(2); g.B[0] = W2t + 0 * HH; g.bias[0] = b2 + 0 * HDIM;
    g.prev[0] = nullptr; g.D[0] = P(5); g.flags[0] = 1 | 4;
    g.A[1] = P(3); g.B[1] = W2t + 2 * HH; g.bias[1] = b2 + 3 * HDIM;
    g.prev[1] = nullptr; g.D[1] = P(6); g.flags[1] = 1 | 4;
    k_gemm<<<dim3(157, 4, 2), 256, 0, stream>>>(g, NNODES, HDIM, HDIM);
  }

  // ---- layer 1 aggregations (dst=0 only): t1 (src type1=P5), t4 (src type3=P6); dst h1_type0=P4
  // outputs -> P0, P1 (zb slices dead)
  {
    AggBatch a{};
    a.src[0] = P(5); a.dst[0] = P(4);
    a.offs[0] = offs + 1 * NNODES; a.rend[0] = cursor + 1 * NNODES;
    a.csr[0] = csr + (size_t)1 * NEDGE; a.out[0] = P(0);
    a.src[1] = P(6); a.dst[1] = P(4);
    a.offs[1] = offs + 3 * NNODES; a.rend[1] = cursor + 3 * NNODES;
    a.csr[1] = csr + (size_t)3 * NEDGE; a.out[1] = P(1);
    k_agg<<<dim3(5000, 2), 256, 0, stream>>>(a);
  }

  // ---- layer 1 MLP first GEMMs: (l=1,t1)->compact 4, (l=1,t4)->compact 5
  {
    const int wj[2] = {4, 5};
    const int bj[2] = {7, 10};  // l*6+t
    GemmBatch g{};
    for (int j = 0; j < 2; ++j) {
      g.A[j] = P(j);
      g.B[j] = W1t + (size_t)wj[j] * HH;
      g.bias[j] = b1 + (size_t)bj[j] * HDIM;
      g.prev[j] = nullptr;
      g.D[j] = P(2 + j);
      g.flags[j] = 1 | 4;
    }
    k_gemm<<<dim3(157, 4, 2), 256, 0, stream>>>(g, NNODES, HDIM, HDIM);
  }

  // ---- layer 1 second GEMMs into out0 (f32; relu deferred to head)
  {
    GemmBatch g{};
    g.A[0] = P(2); g.B[0] = W2t + 4 * HH; g.bias[0] = b2 + 7 * HDIM;
    g.prev[0] = nullptr; g.D[0] = out0; g.flags[0] = 0;
    k_gemm<<<gemm_grid, 256, 0, stream>>>(g, NNODES, HDIM, HDIM);
  }
  {
    GemmBatch g{};
    g.A[0] = P(3); g.B[0] = W2t + 5 * HH; g.bias[0] = b2 + 10 * HDIM;
    g.prev[0] = out0; g.D[0] = out0; g.flags[0] = 2;
    k_gemm<<<gemm_grid, 256, 0, stream>>>(g, NNODES, HDIM, HDIM);
  }

  // ---- head: y = relu(out0) @ W_out + b_out
  k_head<<<5000, 256, 0, stream>>>(out0, W_out, b_out, (float*)d_out);
}

// Round 3
// 688.468 us; speedup vs baseline: 1.2933x; 1.2933x over previous
//
#include <hip/hip_runtime.h>

#define NNODES 20000
#define FIN 64
#define HDIM 512
#define NEDGE 160000

typedef _Float16 f16;
typedef _Float16 f16x8 __attribute__((ext_vector_type(8)));
typedef float f32x4 __attribute__((ext_vector_type(4)));

#define SLICE ((size_t)NNODES * HDIM)
#define HH ((size_t)HDIM * HDIM)

// ---------------------------------------------------------------- helpers
__device__ __forceinline__ void async_lds16(const void* g, void* lds_base) {
  __builtin_amdgcn_global_load_lds(
      (const __attribute__((address_space(1))) void*)g,
      (__attribute__((address_space(3))) void*)lds_base, 16, 0, 0);
}

// ---------------------------------------------------------------- trivial kernels
__global__ void k_zero(int* p, int n) {
  int i = blockIdx.x * 256 + threadIdx.x;
  if (i < n) p[i] = 0;
}

__global__ void k_cvt_x(const float* __restrict__ x, f16* __restrict__ xb, int n) {
  int i = blockIdx.x * 256 + threadIdx.x;
  if (i < n) xb[i] = (f16)x[i];
}

// W_in [5][64][512] -> Wint [5][512][64]
__global__ void k_cvt_win(const float* __restrict__ W, f16* __restrict__ Wt) {
  int i = blockIdx.x * 256 + threadIdx.x;
  if (i >= 5 * 512 * 64) return;
  int t = i >> 15;
  int rem = i & 32767;
  int nn = rem >> 6;
  int kk = rem & 63;
  Wt[i] = (f16)W[(size_t)t * 32768 + (size_t)kk * 512 + nn];
}

// W1/W2 [2][6][512][512] -> transposed f16, compacted to 6 used (l,t) slots
// slot p -> (l*6+t): 0->(0,0) 1->(0,1) 2->(0,3) 3->(0,4) 4->(1,1) 5->(1,4)
__global__ void k_cvt_w12(const float* __restrict__ W1, const float* __restrict__ W2,
                          f16* __restrict__ W1t, f16* __restrict__ W2t) {
  const int LT[6] = {0, 1, 3, 4, 7, 10};
  int i = blockIdx.x * 256 + threadIdx.x;
  if (i >= 6 * 262144) return;
  int p = i >> 18;
  int rem = i & 262143;
  int nn = rem >> 9;
  int kk = rem & 511;
  size_t src = (size_t)LT[p] * 262144 + (size_t)kk * 512 + nn;
  size_t dst = (size_t)p * 262144 + (size_t)nn * 512 + kk;
  W1t[dst] = (f16)W1[src];
  W2t[dst] = (f16)W2[src];
}

// ---------------------------------------------------------------- CSR build
// csr slots c: 0->edge type0, 1->t1, 2->t3, 3->t4
__global__ void k_hist(const int* __restrict__ edges, int* __restrict__ deg) {
  const int TMAP[4] = {0, 1, 3, 4};
  int c = blockIdx.y;
  int t = TMAP[c];
  int e = blockIdx.x * 256 + threadIdx.x;
  if (e < NEDGE) {
    int dst = edges[(size_t)t * 2 * NEDGE + NEDGE + e];
    atomicAdd(&deg[c * NNODES + dst], 1);
  }
}

__global__ void k_scan(const int* __restrict__ deg, int* __restrict__ offs,
                       int* __restrict__ cursor) {
  int c = blockIdx.x;
  const int* d = deg + (size_t)c * NNODES;
  int* o = offs + (size_t)c * NNODES;
  int* cu = cursor + (size_t)c * NNODES;
  __shared__ int sums[256];
  int tid = threadIdx.x;
  const int CH = 79;
  int start = tid * CH;
  int end = min(start + CH, NNODES);
  int s = 0;
  for (int i = start; i < end; ++i) s += d[i];
  sums[tid] = s;
  __syncthreads();
  for (int off = 1; off < 256; off <<= 1) {
    int v = (tid >= off) ? sums[tid - off] : 0;
    __syncthreads();
    sums[tid] += v;
    __syncthreads();
  }
  int run = sums[tid] - s;
  for (int i = start; i < end; ++i) {
    o[i] = run;
    cu[i] = run;
    run += d[i];
  }
}

__global__ void k_scatter(const int* __restrict__ edges, int* __restrict__ cursor,
                          int* __restrict__ csr) {
  const int TMAP[4] = {0, 1, 3, 4};
  int c = blockIdx.y;
  int t = TMAP[c];
  int e = blockIdx.x * 256 + threadIdx.x;
  if (e < NEDGE) {
    int src = edges[(size_t)t * 2 * NEDGE + e];
    int dst = edges[(size_t)t * 2 * NEDGE + NEDGE + e];
    int slot = atomicAdd(&cursor[c * NNODES + dst], 1);
    csr[(size_t)c * NEDGE + slot] = src;
  }
}

// ---------------------------------------------------------------- aggregation
// dst2[j] != null: base = relu(dst + dst2) element-wise, else base = dst.
struct AggBatch {
  const f16* src[4];
  const f16* dst[4];
  const f16* dst2[4];
  const int* offs[4];
  const int* rend[4];
  const int* csr[4];
  f16* out[4];
};

__global__ __launch_bounds__(256) void k_agg(AggBatch ab) {
  int j = blockIdx.y;
  int i = blockIdx.x * 4 + (threadIdx.x >> 6);
  int lane = threadIdx.x & 63;
  float acc[8];
  f16x8 v = *(const f16x8*)(ab.dst[j] + (size_t)i * HDIM + lane * 8);
  if (ab.dst2[j]) {
    f16x8 v2 = *(const f16x8*)(ab.dst2[j] + (size_t)i * HDIM + lane * 8);
#pragma unroll
    for (int q = 0; q < 8; ++q) acc[q] = fmaxf((float)v[q] + (float)v2[q], 0.f);
  } else {
#pragma unroll
    for (int q = 0; q < 8; ++q) acc[q] = (float)v[q];
  }
  int e = ab.offs[j][i];
  int e1 = ab.rend[j][i];
  const int* cs = ab.csr[j];
  const f16* hs = ab.src[j];
  for (; e + 1 < e1; e += 2) {
    int s0 = cs[e], s1 = cs[e + 1];
    f16x8 u0 = *(const f16x8*)(hs + (size_t)s0 * HDIM + lane * 8);
    f16x8 u1 = *(const f16x8*)(hs + (size_t)s1 * HDIM + lane * 8);
#pragma unroll
    for (int q = 0; q < 8; ++q) acc[q] += (float)u0[q] + (float)u1[q];
  }
  if (e < e1) {
    int s0 = cs[e];
    f16x8 u0 = *(const f16x8*)(hs + (size_t)s0 * HDIM + lane * 8);
#pragma unroll
    for (int q = 0; q < 8; ++q) acc[q] += (float)u0[q];
  }
  f16x8 o;
#pragma unroll
  for (int q = 0; q < 8; ++q) o[q] = (f16)acc[q];
  *(f16x8*)(ab.out[j] + (size_t)i * HDIM + lane * 8) = o;
}

// ---------------------------------------------------------------- GEMM (C = A @ Bt^T)
// A [M,K] f16 row-major (stride K), Bt [512,K] f16 row-major.
// flags: 1=relu, 4=f16 out via LDS-bounce coalesced store (else f32 direct).
// Grid: (4 n-blocks, ceil(M/128) m-blocks, z) — n-inner for A L2 reuse.
// K-loop: double-buffered LDS, fine-grained vmcnt(4) + raw s_barrier so
// next-tile global_load_lds overlaps current-tile MFMA.
struct GemmBatch {
  const f16* A[6];
  const f16* B[6];
  const float* bias[6];
  void* D[6];
  int flags[6];
};

__global__ __launch_bounds__(256) void k_gemm(GemmBatch gb, int M, int K) {
  __shared__ __align__(16) char smem[32768];  // 2x8KB A bufs + 2x8KB B bufs; epilogue tile reuses
  const int z = blockIdx.z;
  const f16* __restrict__ A = gb.A[z];
  const f16* __restrict__ Bt = gb.B[z];
  const int flags = gb.flags[z];
  const int tid = threadIdx.x;
  const int lane = tid & 63;
  const int wave = tid >> 6;
  const int n0 = blockIdx.x * 128;
  const int m0 = blockIdx.y * 128;
  const int wm = wave & 1, wn = wave >> 1;
  const int fr = lane & 15, fq = lane >> 4;
  const int r0 = tid >> 2;
  const int co = (tid & 3) * 8;

  // staging source addresses (row-clamped at M edge)
  const f16* gA0 = A + (size_t)min(m0 + r0, M - 1) * K + co;
  const f16* gA1 = A + (size_t)min(m0 + 64 + r0, M - 1) * K + co;
  const f16* gB0 = Bt + (size_t)(n0 + r0) * K + co;
  const f16* gB1 = Bt + (size_t)(n0 + 64 + r0) * K + co;

  f32x4 acc[4][4];
#pragma unroll
  for (int a = 0; a < 4; ++a)
#pragma unroll
    for (int b = 0; b < 4; ++b) acc[a][b] = (f32x4){0.f, 0.f, 0.f, 0.f};

  auto stage = [&](int b, int kk) {
    char* bufA = smem + b * 8192;
    char* bufB = smem + 16384 + b * 8192;
    async_lds16(gA0 + kk, bufA + wave * 1024);
    async_lds16(gA1 + kk, bufA + 4096 + wave * 1024);
    async_lds16(gB0 + kk, bufB + wave * 1024);
    async_lds16(gB1 + kk, bufB + 4096 + wave * 1024);
  };

  const int nb = K >> 5;
  stage(0, 0);
  for (int i = 0; i < nb; ++i) {
    const int cur = i & 1;
    if (i + 1 < nb) {
      stage(cur ^ 1, (i + 1) << 5);
      asm volatile("s_waitcnt vmcnt(4)" ::: "memory");
    } else {
      asm volatile("s_waitcnt vmcnt(0)" ::: "memory");
    }
    asm volatile("s_barrier" ::: "memory");
    const f16* lA = (const f16*)(smem + cur * 8192);
    const f16* lB = (const f16*)(smem + 16384 + cur * 8192);
    f16x8 af[4], bf[4];
#pragma unroll
    for (int t = 0; t < 4; ++t)
      af[t] = *(const f16x8*)&lA[(wm * 64 + t * 16 + fr) * 32 + fq * 8];
#pragma unroll
    for (int t = 0; t < 4; ++t)
      bf[t] = *(const f16x8*)&lB[(wn * 64 + t * 16 + fr) * 32 + fq * 8];
#pragma unroll
    for (int mt = 0; mt < 4; ++mt)
#pragma unroll
      for (int nt = 0; nt < 4; ++nt)
        acc[mt][nt] = __builtin_amdgcn_mfma_f32_16x16x32_f16(af[mt], bf[nt], acc[mt][nt], 0, 0, 0);
    asm volatile("s_barrier" ::: "memory");  // cur consumed; safe to restage next iter
  }

  const float* __restrict__ bias = gb.bias[z];

  if (flags & 4) {
    // f16 output via LDS bounce: 2 passes of 64 rows, padded stride 136 f16
    f16* tile = (f16*)smem;
#pragma unroll
    for (int pass = 0; pass < 2; ++pass) {
      if (wm == pass) {
#pragma unroll
        for (int nt = 0; nt < 4; ++nt) {
          const int col = n0 + wn * 64 + nt * 16 + fr;
          const float bv = bias[col];
#pragma unroll
          for (int mt = 0; mt < 4; ++mt) {
#pragma unroll
            for (int r = 0; r < 4; ++r) {
              float v = acc[mt][nt][r] + bv;
              if (flags & 1) v = fmaxf(v, 0.f);
              tile[(mt * 16 + fq * 4 + r) * 136 + wn * 64 + nt * 16 + fr] = (f16)v;
            }
          }
        }
      }
      __syncthreads();
#pragma unroll
      for (int q = 0; q < 4; ++q) {
        int idx = q * 256 + tid;
        int row = idx >> 4;
        int c8 = idx & 15;
        int grow = m0 + pass * 64 + row;
        f16x8 val = *(const f16x8*)&tile[row * 136 + c8 * 8];
        if (grow < M)
          *(f16x8*)((f16*)gb.D[z] + (size_t)grow * HDIM + n0 + c8 * 8) = val;
      }
      __syncthreads();
    }
  } else {
    // f32 direct store (64B/quarter-wave granules — clean)
#pragma unroll
    for (int nt = 0; nt < 4; ++nt) {
      const int col = n0 + wn * 64 + nt * 16 + fr;
      const float bv = bias[col];
#pragma unroll
      for (int mt = 0; mt < 4; ++mt) {
        const int rowb = m0 + wm * 64 + mt * 16 + fq * 4;
#pragma unroll
        for (int r = 0; r < 4; ++r) {
          int row = rowb + r;
          if (row < M) {
            float v = acc[mt][nt][r] + bv;
            if (flags & 1) v = fmaxf(v, 0.f);
            ((float*)gb.D[z])[(size_t)row * HDIM + col] = v;
          }
        }
      }
    }
  }
}

// ---------------------------------------------------------------- head
// y = relu(oa + ob) @ W_out + b_out   (oa, ob f32 [20000,512])
__global__ __launch_bounds__(256) void k_head(const float* __restrict__ oa,
                                              const float* __restrict__ ob,
                                              const float* __restrict__ Wout,
                                              const float* __restrict__ bout,
                                              float* __restrict__ y) {
  int i = blockIdx.x * 4 + (threadIdx.x >> 6);
  int lane = threadIdx.x & 63;
  const float4* ra = (const float4*)(oa + (size_t)i * HDIM);
  const float4* rb = (const float4*)(ob + (size_t)i * HDIM);
  const float4* w = (const float4*)Wout;
  float s = 0.f;
#pragma unroll
  for (int h = 0; h < 2; ++h) {
    float4 a = ra[h * 64 + lane], b = rb[h * 64 + lane], ww = w[h * 64 + lane];
    s += fmaxf(a.x + b.x, 0.f) * ww.x + fmaxf(a.y + b.y, 0.f) * ww.y +
         fmaxf(a.z + b.z, 0.f) * ww.z + fmaxf(a.w + b.w, 0.f) * ww.w;
  }
#pragma unroll
  for (int m = 32; m; m >>= 1) s += __shfl_xor(s, m, 64);
  if (lane == 0) y[i] = s + bout[0];
}

// ---------------------------------------------------------------- launch
extern "C" void kernel_launch(void* const* d_in, const int* in_sizes, int n_in,
                              void* d_out, int out_size, void* d_ws, size_t ws_size,
                              hipStream_t stream) {
  const float* x_all = (const float*)d_in[0];
  const float* W_in = (const float*)d_in[1];
  const float* b_in = (const float*)d_in[2];
  const float* W1 = (const float*)d_in[3];
  const float* b1 = (const float*)d_in[4];
  const float* W2 = (const float*)d_in[5];
  const float* b2 = (const float*)d_in[6];
  const float* W_out = (const float*)d_in[7];
  const float* b_out = (const float*)d_in[8];
  const int* edges = (const int*)d_in[9];

  // ---- workspace carve (~207 MB)
  char* p = (char*)d_ws;
  auto take = [&](size_t bytes) {
    char* r = p;
    p += (bytes + 255) & ~(size_t)255;
    return r;
  };
  f16* xb = (f16*)take((size_t)5 * NNODES * FIN * 2);
  f16* Wint = (f16*)take((size_t)5 * HDIM * FIN * 2);
  f16* W1t = (f16*)take((size_t)6 * HH * 2);
  f16* W2t = (f16*)take((size_t)6 * HH * 2);
  int* deg = (int*)take((size_t)4 * NNODES * 4);
  int* offs = (int*)take((size_t)4 * NNODES * 4);
  int* cursor = (int*)take((size_t)4 * NNODES * 4);
  int* csr = (int*)take((size_t)4 * NEDGE * 4);
  f16* pool = (f16*)take((size_t)9 * SLICE * 2);
  auto P = [&](int s) { return pool + (size_t)s * SLICE; };

  // ---- prep
  k_zero<<<(4 * NNODES + 255) / 256, 256, 0, stream>>>(deg, 4 * NNODES);
  k_cvt_x<<<(5 * NNODES * FIN) / 256, 256, 0, stream>>>(x_all, xb, 5 * NNODES * FIN);
  k_cvt_win<<<640, 256, 0, stream>>>(W_in, Wint);
  k_cvt_w12<<<6144, 256, 0, stream>>>(W1, W2, W1t, W2t);
  k_hist<<<dim3(625, 4), 256, 0, stream>>>(edges, deg);
  k_scan<<<4, 256, 0, stream>>>(deg, offs, cursor);
  k_scatter<<<dim3(625, 4), 256, 0, stream>>>(edges, cursor, csr);

  // ---- input projection: h0 types {0->P0,1->P1,2->P2,3->P3,4->P7}
  {
    const int hs[5] = {0, 1, 2, 3, 7};
    GemmBatch g{};
    for (int t = 0; t < 5; ++t) {
      g.A[t] = xb + (size_t)t * NNODES * FIN;
      g.B[t] = Wint + (size_t)t * HDIM * FIN;
      g.bias[t] = b_in + (size_t)t * HDIM;
      g.D[t] = P(hs[t]);
      g.flags[t] = 1 | 4;
    }
    k_gemm<<<dim3(4, 157, 5), 256, 0, stream>>>(g, NNODES, FIN);
  }

  // ---- layer 0 aggregations: t1->P4, t4->P5, t0->P6, t3->P8
  {
    AggBatch a{};
    a.src[0] = P(1); a.dst[0] = P(0);
    a.offs[0] = offs + 1 * NNODES; a.rend[0] = cursor + 1 * NNODES;
    a.csr[0] = csr + (size_t)1 * NEDGE; a.out[0] = P(4);
    a.src[1] = P(3); a.dst[1] = P(0);
    a.offs[1] = offs + 3 * NNODES; a.rend[1] = cursor + 3 * NNODES;
    a.csr[1] = csr + (size_t)3 * NEDGE; a.out[1] = P(5);
    a.src[2] = P(7); a.dst[2] = P(1);
    a.offs[2] = offs + 0 * NNODES; a.rend[2] = cursor + 0 * NNODES;
    a.csr[2] = csr + (size_t)0 * NEDGE; a.out[2] = P(6);
    a.src[3] = P(2); a.dst[3] = P(3);
    a.offs[3] = offs + 2 * NNODES; a.rend[3] = cursor + 2 * NNODES;
    a.csr[3] = csr + (size_t)2 * NEDGE; a.out[3] = P(8);
    k_agg<<<dim3(5000, 4), 256, 0, stream>>>(a);
  }

  // ---- layer 0 MLP first GEMMs: A {P4,P5,P6,P8} -> z {P0,P1,P2,P3}
  {
    const int aj[4] = {4, 5, 6, 8};
    const int wj[4] = {1, 3, 0, 2};
    const int bj[4] = {1, 4, 0, 3};
    GemmBatch g{};
    for (int j = 0; j < 4; ++j) {
      g.A[j] = P(aj[j]);
      g.B[j] = W1t + (size_t)wj[j] * HH;
      g.bias[j] = b1 + (size_t)bj[j] * HDIM;
      g.D[j] = P(j);
      g.flags[j] = 1 | 4;
    }
    k_gemm<<<dim3(4, 157, 4), 256, 0, stream>>>(g, NNODES, HDIM);
  }

  // ---- layer 0 second GEMMs (one z=4 batch, all independent):
  // t1: ya->P4 (no relu), t4: yb->P5 (no relu), t0: h1_t1->P6 (relu), t3: h1_t3->P7 (relu)
  {
    const int wj[4] = {1, 3, 0, 2};
    const int bj[4] = {1, 4, 0, 3};
    const int dj[4] = {4, 5, 6, 7};
    const int fl[4] = {4, 4, 1 | 4, 1 | 4};
    GemmBatch g{};
    for (int j = 0; j < 4; ++j) {
      g.A[j] = P(j);
      g.B[j] = W2t + (size_t)wj[j] * HH;
      g.bias[j] = b2 + (size_t)bj[j] * HDIM;
      g.D[j] = P(dj[j]);
      g.flags[j] = fl[j];
    }
    k_gemm<<<dim3(4, 157, 4), 256, 0, stream>>>(g, NNODES, HDIM);
  }

  // ---- layer 1 aggregations: dst = relu(P4+P5) fused; srcs P6,P7 -> out P0,P1
  {
    AggBatch a{};
    a.src[0] = P(6); a.dst[0] = P(4); a.dst2[0] = P(5);
    a.offs[0] = offs + 1 * NNODES; a.rend[0] = cursor + 1 * NNODES;
    a.csr[0] = csr + (size_t)1 * NEDGE; a.out[0] = P(0);
    a.src[1] = P(7); a.dst[1] = P(4); a.dst2[1] = P(5);
    a.offs[1] = offs + 3 * NNODES; a.rend[1] = cursor + 3 * NNODES;
    a.csr[1] = csr + (size_t)3 * NEDGE; a.out[1] = P(1);
    k_agg<<<dim3(5000, 2), 256, 0, stream>>>(a);
  }

  // ---- layer 1 MLP first GEMMs: {P0,P1} -> {P2,P3}
  {
    const int wj[2] = {4, 5};
    const int bj[2] = {7, 10};
    GemmBatch g{};
    for (int j = 0; j < 2; ++j) {
      g.A[j] = P(j);
      g.B[j] = W1t + (size_t)wj[j] * HH;
      g.bias[j] = b1 + (size_t)bj[j] * HDIM;
      g.D[j] = P(2 + j);
      g.flags[j] = 1 | 4;
    }
    k_gemm<<<dim3(4, 157, 2), 256, 0, stream>>>(g, NNODES, HDIM);
  }

  // ---- layer 1 second GEMMs (z=2, f32 outputs): oa -> P4/P5 region, ob -> P6/P7 region
  float* oa = (float*)P(4);
  float* ob = (float*)P(6);
  {
    const int wj[2] = {4, 5};
    const int bj[2] = {7, 10};
    GemmBatch g{};
    g.A[0] = P(2); g.B[0] = W2t + (size_t)wj[0] * HH;
    g.bias[0] = b2 + (size_t)bj[0] * HDIM; g.D[0] = oa; g.flags[0] = 0;
    g.A[1] = P(3); g.B[1] = W2t + (size_t)wj[1] * HH;
    g.bias[1] = b2 + (size_t)bj[1] * HDIM; g.D[1] = ob; g.flags[1] = 0;
    k_gemm<<<dim3(4, 157, 2), 256, 0, stream>>>(g, NNODES, HDIM);
  }

  // ---- head
  k_head<<<5000, 256, 0, stream>>>(oa, ob, W_out, b_out, (float*)d_out);
}

// Round 4
// 648.889 us; speedup vs baseline: 1.3722x; 1.0610x over previous
//
#include <hip/hip_runtime.h>

#define NNODES 20000
#define FIN 64
#define HDIM 512
#define NEDGE 160000

typedef _Float16 f16;
typedef _Float16 f16x8 __attribute__((ext_vector_type(8)));
typedef float f32x4 __attribute__((ext_vector_type(4)));

#define SLICE ((size_t)NNODES * HDIM)
#define HH ((size_t)HDIM * HDIM)

// ---------------------------------------------------------------- helpers
__device__ __forceinline__ void async_lds16(const void* g, void* lds_base) {
  __builtin_amdgcn_global_load_lds(
      (const __attribute__((address_space(1))) void*)g,
      (__attribute__((address_space(3))) void*)lds_base, 16, 0, 0);
}

// ---------------------------------------------------------------- fused prep
// blocks [0,313): zero deg (80000 ints)
// blocks [313,25313): cvt x_all -> f16 (6.4M)
// blocks [25313,25953): W_in [5][64][512] -> [5][512][64] f16
// blocks [25953,32097): W1/W2 -> transposed f16, 6 used (l,t) slots
__global__ void k_prep(const float* __restrict__ x, f16* __restrict__ xb,
                       const float* __restrict__ Win, f16* __restrict__ Wint,
                       const float* __restrict__ W1, const float* __restrict__ W2,
                       f16* __restrict__ W1t, f16* __restrict__ W2t,
                       int* __restrict__ deg) {
  int b = blockIdx.x;
  if (b < 313) {
    int i = b * 256 + threadIdx.x;
    if (i < 4 * NNODES) deg[i] = 0;
  } else if (b < 25313) {
    int i = (b - 313) * 256 + threadIdx.x;
    xb[i] = (f16)x[i];
  } else if (b < 25953) {
    int i = (b - 25313) * 256 + threadIdx.x;
    int t = i >> 15;
    int rem = i & 32767;
    int nn = rem >> 6;
    int kk = rem & 63;
    Wint[i] = (f16)Win[(size_t)t * 32768 + (size_t)kk * 512 + nn];
  } else {
    const int LT[6] = {0, 1, 3, 4, 7, 10};
    int i = (b - 25953) * 256 + threadIdx.x;
    int p = i >> 18;
    int rem = i & 262143;
    int nn = rem >> 9;
    int kk = rem & 511;
    size_t src = (size_t)LT[p] * 262144 + (size_t)kk * 512 + nn;
    size_t dst = (size_t)p * 262144 + (size_t)nn * 512 + kk;
    W1t[dst] = (f16)W1[src];
    W2t[dst] = (f16)W2[src];
  }
}

// ---------------------------------------------------------------- CSR build
// csr slots c: 0->edge type0, 1->t1, 2->t3, 3->t4
__global__ void k_hist(const int* __restrict__ edges, int* __restrict__ deg) {
  const int TMAP[4] = {0, 1, 3, 4};
  int c = blockIdx.y;
  int t = TMAP[c];
  int e = blockIdx.x * 256 + threadIdx.x;
  if (e < NEDGE) {
    int dst = edges[(size_t)t * 2 * NEDGE + NEDGE + e];
    atomicAdd(&deg[c * NNODES + dst], 1);
  }
}

__global__ void k_scan(const int* __restrict__ deg, int* __restrict__ offs,
                       int* __restrict__ cursor) {
  int c = blockIdx.x;
  const int* d = deg + (size_t)c * NNODES;
  int* o = offs + (size_t)c * NNODES;
  int* cu = cursor + (size_t)c * NNODES;
  __shared__ int sums[256];
  int tid = threadIdx.x;
  const int CH = 79;
  int start = tid * CH;
  int end = min(start + CH, NNODES);
  int s = 0;
  for (int i = start; i < end; ++i) s += d[i];
  sums[tid] = s;
  __syncthreads();
  for (int off = 1; off < 256; off <<= 1) {
    int v = (tid >= off) ? sums[tid - off] : 0;
    __syncthreads();
    sums[tid] += v;
    __syncthreads();
  }
  int run = sums[tid] - s;
  for (int i = start; i < end; ++i) {
    o[i] = run;
    cu[i] = run;
    run += d[i];
  }
}

__global__ void k_scatter(const int* __restrict__ edges, int* __restrict__ cursor,
                          int* __restrict__ csr) {
  const int TMAP[4] = {0, 1, 3, 4};
  int c = blockIdx.y;
  int t = TMAP[c];
  int e = blockIdx.x * 256 + threadIdx.x;
  if (e < NEDGE) {
    int src = edges[(size_t)t * 2 * NEDGE + e];
    int dst = edges[(size_t)t * 2 * NEDGE + NEDGE + e];
    int slot = atomicAdd(&cursor[c * NNODES + dst], 1);
    csr[(size_t)c * NEDGE + slot] = src;
  }
}

// ---------------------------------------------------------------- aggregation v2
// Per slot: base = dst (or relu(dst+dst2)); out1 = base + sum(csr1 gather of src1);
// optional second list sharing the same base.
struct AggSlot {
  const f16* dst;
  const f16* dst2;   // nullable: base = relu(dst+dst2)
  const f16* src1;
  const int* offs1;
  const int* rend1;
  const int* csr1;
  f16* out1;
  const f16* src2;   // nullable: second list
  const int* offs2;
  const int* rend2;
  const int* csr2;
  f16* out2;
};
struct AggBatch { AggSlot s[3]; };

__device__ __forceinline__ void agg_list(const f16* __restrict__ hs,
                                         const int* __restrict__ cs,
                                         int e, int e1, int lane,
                                         const float* __restrict__ base,
                                         f16* __restrict__ outp) {
  float acc[8];
#pragma unroll
  for (int q = 0; q < 8; ++q) acc[q] = base[q];
  for (; e + 3 < e1; e += 4) {
    int s0 = cs[e], s1 = cs[e + 1], s2 = cs[e + 2], s3 = cs[e + 3];
    f16x8 u0 = *(const f16x8*)(hs + (size_t)s0 * HDIM + lane * 8);
    f16x8 u1 = *(const f16x8*)(hs + (size_t)s1 * HDIM + lane * 8);
    f16x8 u2 = *(const f16x8*)(hs + (size_t)s2 * HDIM + lane * 8);
    f16x8 u3 = *(const f16x8*)(hs + (size_t)s3 * HDIM + lane * 8);
#pragma unroll
    for (int q = 0; q < 8; ++q)
      acc[q] += ((float)u0[q] + (float)u1[q]) + ((float)u2[q] + (float)u3[q]);
  }
  for (; e < e1; ++e) {
    int s0 = cs[e];
    f16x8 u0 = *(const f16x8*)(hs + (size_t)s0 * HDIM + lane * 8);
#pragma unroll
    for (int q = 0; q < 8; ++q) acc[q] += (float)u0[q];
  }
  f16x8 o;
#pragma unroll
  for (int q = 0; q < 8; ++q) o[q] = (f16)acc[q];
  *(f16x8*)outp = o;
}

__global__ __launch_bounds__(256) void k_agg(AggBatch ab) {
  const AggSlot sl = ab.s[blockIdx.y];
  int i = blockIdx.x * 4 + (threadIdx.x >> 6);
  int lane = threadIdx.x & 63;
  const size_t off = (size_t)i * HDIM + lane * 8;
  float base[8];
  f16x8 v = *(const f16x8*)(sl.dst + off);
  if (sl.dst2) {
    f16x8 v2 = *(const f16x8*)(sl.dst2 + off);
#pragma unroll
    for (int q = 0; q < 8; ++q) base[q] = fmaxf((float)v[q] + (float)v2[q], 0.f);
  } else {
#pragma unroll
    for (int q = 0; q < 8; ++q) base[q] = (float)v[q];
  }
  agg_list(sl.src1, sl.csr1, sl.offs1[i], sl.rend1[i], lane, base, sl.out1 + off);
  if (sl.src2)
    agg_list(sl.src2, sl.csr2, sl.offs2[i], sl.rend2[i], lane, base, sl.out2 + off);
}

// ---------------------------------------------------------------- GEMM (C = A @ Bt^T)
// Tile 128(M) x 256(N), BK=32, 4 waves each 64x128 (4x8 fragments).
// A [M,K] f16 row-major, Bt [512,K] f16 row-major.
// flags: 1=relu, 4=f16 out via LDS-bounce (else f32 direct).
// Grid: (2 n-blocks, ceil(M/128) m-blocks, z).
struct GemmBatch {
  const f16* A[6];
  const f16* B[6];
  const float* bias[6];
  void* D[6];
  int flags[6];
};

__global__ __launch_bounds__(256, 2) void k_gemm(GemmBatch gb, int M, int K) {
  __shared__ __align__(16) char smem[49152];  // A: 2x8KB @0; B: 2x16KB @16384
  const int z = blockIdx.z;
  const f16* __restrict__ A = gb.A[z];
  const f16* __restrict__ Bt = gb.B[z];
  const int flags = gb.flags[z];
  const int tid = threadIdx.x;
  const int lane = tid & 63;
  const int wave = tid >> 6;
  const int n0 = blockIdx.x * 256;
  const int m0 = blockIdx.y * 128;
  const int wm = wave & 1, wn = wave >> 1;
  const int fr = lane & 15, fq = lane >> 4;

  // staging addresses: each wave-call stages 16 rows x 64B
  const int lr = lane >> 2;          // row within 16-row group
  const int lc = (lane & 3) * 8;     // f16 col offset
  const f16* gA0 = A + (size_t)min(m0 + (wave * 2 + 0) * 16 + lr, M - 1) * K + lc;
  const f16* gA1 = A + (size_t)min(m0 + (wave * 2 + 1) * 16 + lr, M - 1) * K + lc;
  const f16* gB0 = Bt + (size_t)(n0 + (wave * 4 + 0) * 16 + lr) * K + lc;
  const f16* gB1 = Bt + (size_t)(n0 + (wave * 4 + 1) * 16 + lr) * K + lc;
  const f16* gB2 = Bt + (size_t)(n0 + (wave * 4 + 2) * 16 + lr) * K + lc;
  const f16* gB3 = Bt + (size_t)(n0 + (wave * 4 + 3) * 16 + lr) * K + lc;

  f32x4 acc[4][8];
#pragma unroll
  for (int a = 0; a < 4; ++a)
#pragma unroll
    for (int b = 0; b < 8; ++b) acc[a][b] = (f32x4){0.f, 0.f, 0.f, 0.f};

  auto stage = [&](int b, int kk) {
    char* bufA = smem + b * 8192;
    char* bufB = smem + 16384 + b * 16384;
    async_lds16(gA0 + kk, bufA + (wave * 2 + 0) * 1024);
    async_lds16(gA1 + kk, bufA + (wave * 2 + 1) * 1024);
    async_lds16(gB0 + kk, bufB + (wave * 4 + 0) * 1024);
    async_lds16(gB1 + kk, bufB + (wave * 4 + 1) * 1024);
    async_lds16(gB2 + kk, bufB + (wave * 4 + 2) * 1024);
    async_lds16(gB3 + kk, bufB + (wave * 4 + 3) * 1024);
  };

  const int nb = K >> 5;
  stage(0, 0);
  for (int i = 0; i < nb; ++i) {
    const int cur = i & 1;
    if (i + 1 < nb) {
      stage(cur ^ 1, (i + 1) << 5);
      asm volatile("s_waitcnt vmcnt(6)" ::: "memory");
    } else {
      asm volatile("s_waitcnt vmcnt(0)" ::: "memory");
    }
    asm volatile("s_barrier" ::: "memory");
    const f16* lA = (const f16*)(smem + cur * 8192);
    const f16* lB = (const f16*)(smem + 16384 + cur * 16384);
    f16x8 af[4], bf[8];
#pragma unroll
    for (int t = 0; t < 4; ++t)
      af[t] = *(const f16x8*)&lA[(wm * 64 + t * 16 + fr) * 32 + fq * 8];
#pragma unroll
    for (int t = 0; t < 8; ++t)
      bf[t] = *(const f16x8*)&lB[(wn * 128 + t * 16 + fr) * 32 + fq * 8];
#pragma unroll
    for (int mt = 0; mt < 4; ++mt)
#pragma unroll
      for (int nt = 0; nt < 8; ++nt)
        acc[mt][nt] = __builtin_amdgcn_mfma_f32_16x16x32_f16(af[mt], bf[nt], acc[mt][nt], 0, 0, 0);
    asm volatile("s_barrier" ::: "memory");
  }

  const float* __restrict__ bias = gb.bias[z];

  if (flags & 4) {
    // f16 out via LDS bounce: 2 passes of 64 rows, padded stride 264 f16
    f16* tile = (f16*)smem;
#pragma unroll
    for (int pass = 0; pass < 2; ++pass) {
      if (wm == pass) {
#pragma unroll
        for (int nt = 0; nt < 8; ++nt) {
          const int cl = wn * 128 + nt * 16 + fr;
          const float bv = bias[n0 + cl];
#pragma unroll
          for (int mt = 0; mt < 4; ++mt) {
#pragma unroll
            for (int r = 0; r < 4; ++r) {
              float v = acc[mt][nt][r] + bv;
              if (flags & 1) v = fmaxf(v, 0.f);
              tile[(mt * 16 + fq * 4 + r) * 264 + cl] = (f16)v;
            }
          }
        }
      }
      __syncthreads();
#pragma unroll
      for (int q = 0; q < 8; ++q) {
        int idx = q * 256 + tid;
        int row = idx >> 5;
        int c8 = idx & 31;
        int grow = m0 + pass * 64 + row;
        f16x8 val = *(const f16x8*)&tile[row * 264 + c8 * 8];
        if (grow < M)
          *(f16x8*)((f16*)gb.D[z] + (size_t)grow * HDIM + n0 + c8 * 8) = val;
      }
      __syncthreads();
    }
  } else {
#pragma unroll
    for (int nt = 0; nt < 8; ++nt) {
      const int col = n0 + wn * 128 + nt * 16 + fr;
      const float bv = bias[col];
#pragma unroll
      for (int mt = 0; mt < 4; ++mt) {
        const int rowb = m0 + wm * 64 + mt * 16 + fq * 4;
#pragma unroll
        for (int r = 0; r < 4; ++r) {
          int row = rowb + r;
          if (row < M) {
            float v = acc[mt][nt][r] + bv;
            if (flags & 1) v = fmaxf(v, 0.f);
            ((float*)gb.D[z])[(size_t)row * HDIM + col] = v;
          }
        }
      }
    }
  }
}

// ---------------------------------------------------------------- head
__global__ __launch_bounds__(256) void k_head(const float* __restrict__ oa,
                                              const float* __restrict__ ob,
                                              const float* __restrict__ Wout,
                                              const float* __restrict__ bout,
                                              float* __restrict__ y) {
  int i = blockIdx.x * 4 + (threadIdx.x >> 6);
  int lane = threadIdx.x & 63;
  const float4* ra = (const float4*)(oa + (size_t)i * HDIM);
  const float4* rb = (const float4*)(ob + (size_t)i * HDIM);
  const float4* w = (const float4*)Wout;
  float s = 0.f;
#pragma unroll
  for (int h = 0; h < 2; ++h) {
    float4 a = ra[h * 64 + lane], b = rb[h * 64 + lane], ww = w[h * 64 + lane];
    s += fmaxf(a.x + b.x, 0.f) * ww.x + fmaxf(a.y + b.y, 0.f) * ww.y +
         fmaxf(a.z + b.z, 0.f) * ww.z + fmaxf(a.w + b.w, 0.f) * ww.w;
  }
#pragma unroll
  for (int m = 32; m; m >>= 1) s += __shfl_xor(s, m, 64);
  if (lane == 0) y[i] = s + bout[0];
}

// ---------------------------------------------------------------- launch
extern "C" void kernel_launch(void* const* d_in, const int* in_sizes, int n_in,
                              void* d_out, int out_size, void* d_ws, size_t ws_size,
                              hipStream_t stream) {
  const float* x_all = (const float*)d_in[0];
  const float* W_in = (const float*)d_in[1];
  const float* b_in = (const float*)d_in[2];
  const float* W1 = (const float*)d_in[3];
  const float* b1 = (const float*)d_in[4];
  const float* W2 = (const float*)d_in[5];
  const float* b2 = (const float*)d_in[6];
  const float* W_out = (const float*)d_in[7];
  const float* b_out = (const float*)d_in[8];
  const int* edges = (const int*)d_in[9];

  // ---- workspace carve (~207 MB)
  char* p = (char*)d_ws;
  auto take = [&](size_t bytes) {
    char* r = p;
    p += (bytes + 255) & ~(size_t)255;
    return r;
  };
  f16* xb = (f16*)take((size_t)5 * NNODES * FIN * 2);
  f16* Wint = (f16*)take((size_t)5 * HDIM * FIN * 2);
  f16* W1t = (f16*)take((size_t)6 * HH * 2);
  f16* W2t = (f16*)take((size_t)6 * HH * 2);
  int* deg = (int*)take((size_t)4 * NNODES * 4);
  int* offs = (int*)take((size_t)4 * NNODES * 4);
  int* cursor = (int*)take((size_t)4 * NNODES * 4);
  int* csr = (int*)take((size_t)4 * NEDGE * 4);
  f16* pool = (f16*)take((size_t)9 * SLICE * 2);
  auto P = [&](int s) { return pool + (size_t)s * SLICE; };

  // ---- prep + CSR
  k_prep<<<32097, 256, 0, stream>>>(x_all, xb, W_in, Wint, W1, W2, W1t, W2t, deg);
  k_hist<<<dim3(625, 4), 256, 0, stream>>>(edges, deg);
  k_scan<<<4, 256, 0, stream>>>(deg, offs, cursor);
  k_scatter<<<dim3(625, 4), 256, 0, stream>>>(edges, cursor, csr);

  // ---- input projection: h0 types {0->P0,1->P1,2->P2,3->P3,4->P7}
  {
    const int hs[5] = {0, 1, 2, 3, 7};
    GemmBatch g{};
    for (int t = 0; t < 5; ++t) {
      g.A[t] = xb + (size_t)t * NNODES * FIN;
      g.B[t] = Wint + (size_t)t * HDIM * FIN;
      g.bias[t] = b_in + (size_t)t * HDIM;
      g.D[t] = P(hs[t]);
      g.flags[t] = 1 | 4;
    }
    k_gemm<<<dim3(2, 157, 5), 256, 0, stream>>>(g, NNODES, FIN);
  }

  // ---- layer 0 aggregations: slot0 pair(t1->P4, t4->P5, dst P0); slot1 t0->P6; slot2 t3->P8
  {
    AggBatch a{};
    a.s[0].dst = P(0);
    a.s[0].src1 = P(1); a.s[0].offs1 = offs + 1 * NNODES;
    a.s[0].rend1 = cursor + 1 * NNODES; a.s[0].csr1 = csr + (size_t)1 * NEDGE;
    a.s[0].out1 = P(4);
    a.s[0].src2 = P(3); a.s[0].offs2 = offs + 3 * NNODES;
    a.s[0].rend2 = cursor + 3 * NNODES; a.s[0].csr2 = csr + (size_t)3 * NEDGE;
    a.s[0].out2 = P(5);
    a.s[1].dst = P(1);
    a.s[1].src1 = P(7); a.s[1].offs1 = offs + 0 * NNODES;
    a.s[1].rend1 = cursor + 0 * NNODES; a.s[1].csr1 = csr + (size_t)0 * NEDGE;
    a.s[1].out1 = P(6);
    a.s[2].dst = P(3);
    a.s[2].src1 = P(2); a.s[2].offs1 = offs + 2 * NNODES;
    a.s[2].rend1 = cursor + 2 * NNODES; a.s[2].csr1 = csr + (size_t)2 * NEDGE;
    a.s[2].out1 = P(8);
    k_agg<<<dim3(5000, 3), 256, 0, stream>>>(a);
  }

  // ---- layer 0 MLP first GEMMs: A {P4,P5,P6,P8} -> z {P0,P1,P2,P3}
  {
    const int aj[4] = {4, 5, 6, 8};
    const int wj[4] = {1, 3, 0, 2};
    const int bj[4] = {1, 4, 0, 3};
    GemmBatch g{};
    for (int j = 0; j < 4; ++j) {
      g.A[j] = P(aj[j]);
      g.B[j] = W1t + (size_t)wj[j] * HH;
      g.bias[j] = b1 + (size_t)bj[j] * HDIM;
      g.D[j] = P(j);
      g.flags[j] = 1 | 4;
    }
    k_gemm<<<dim3(2, 157, 4), 256, 0, stream>>>(g, NNODES, HDIM);
  }

  // ---- layer 0 second GEMMs: ya->P4, yb->P5 (no relu); h1_t1->P6, h1_t3->P7 (relu)
  {
    const int wj[4] = {1, 3, 0, 2};
    const int bj[4] = {1, 4, 0, 3};
    const int dj[4] = {4, 5, 6, 7};
    const int fl[4] = {4, 4, 1 | 4, 1 | 4};
    GemmBatch g{};
    for (int j = 0; j < 4; ++j) {
      g.A[j] = P(j);
      g.B[j] = W2t + (size_t)wj[j] * HH;
      g.bias[j] = b2 + (size_t)bj[j] * HDIM;
      g.D[j] = P(dj[j]);
      g.flags[j] = fl[j];
    }
    k_gemm<<<dim3(2, 157, 4), 256, 0, stream>>>(g, NNODES, HDIM);
  }

  // ---- layer 1 aggregation: one paired slot, dst = relu(P4+P5); srcs P6,P7 -> P0,P1
  {
    AggBatch a{};
    a.s[0].dst = P(4); a.s[0].dst2 = P(5);
    a.s[0].src1 = P(6); a.s[0].offs1 = offs + 1 * NNODES;
    a.s[0].rend1 = cursor + 1 * NNODES; a.s[0].csr1 = csr + (size_t)1 * NEDGE;
    a.s[0].out1 = P(0);
    a.s[0].src2 = P(7); a.s[0].offs2 = offs + 3 * NNODES;
    a.s[0].rend2 = cursor + 3 * NNODES; a.s[0].csr2 = csr + (size_t)3 * NEDGE;
    a.s[0].out2 = P(1);
    k_agg<<<dim3(5000, 1), 256, 0, stream>>>(a);
  }

  // ---- layer 1 MLP first GEMMs: {P0,P1} -> {P2,P3}
  {
    const int wj[2] = {4, 5};
    const int bj[2] = {7, 10};
    GemmBatch g{};
    for (int j = 0; j < 2; ++j) {
      g.A[j] = P(j);
      g.B[j] = W1t + (size_t)wj[j] * HH;
      g.bias[j] = b1 + (size_t)bj[j] * HDIM;
      g.D[j] = P(2 + j);
      g.flags[j] = 1 | 4;
    }
    k_gemm<<<dim3(2, 157, 2), 256, 0, stream>>>(g, NNODES, HDIM);
  }

  // ---- layer 1 second GEMMs (z=2, f32 outputs): oa -> P4/P5, ob -> P6/P7
  float* oa = (float*)P(4);
  float* ob = (float*)P(6);
  {
    GemmBatch g{};
    g.A[0] = P(2); g.B[0] = W2t + (size_t)4 * HH;
    g.bias[0] = b2 + (size_t)7 * HDIM; g.D[0] = oa; g.flags[0] = 0;
    g.A[1] = P(3); g.B[1] = W2t + (size_t)5 * HH;
    g.bias[1] = b2 + (size_t)10 * HDIM; g.D[1] = ob; g.flags[1] = 0;
    k_gemm<<<dim3(2, 157, 2), 256, 0, stream>>>(g, NNODES, HDIM);
  }

  // ---- head
  k_head<<<5000, 256, 0, stream>>>(oa, ob, W_out, b_out, (float*)d_out);
}